// Round 8
// baseline (433.066 us; speedup 1.0000x reference)
//
#include <hip/hip_runtime.h>
#include <stdint.h>

#define N_TOK    16384
#define E_DIM    256
#define N_CODE   5120
#define N_SHARED 2048
#define BIGF     1e7f

#define BM  256
#define BN  128
#define BK  32
#define NCB (N_CODE / BN)           // 40 column blocks
#define NKT (E_DIM / BK)            // 8 K-tiles
#define CHUNK_A (BM * BK)           // 8192 shorts = 16 KB per stream per K-tile
#define CHUNK_B (BN * BK)           // 4096 shorts = 8 KB per stream per K-tile
#define NBLK (NCB * (N_TOK / BM))   // 2560 blocks, %8 == 0 -> simple XCD swizzle bijective

#define IDX_OFF ((size_t)N_TOK * E_DIM)                    // 4194304
#define D_OFF   (IDX_OFF + N_TOK)                          // 4210688
#define QL_OFF  (D_OFF + (size_t)N_TOK * N_CODE)           // 88096768

typedef float f32x4 __attribute__((ext_vector_type(4)));
typedef short bf16x8 __attribute__((ext_vector_type(8)));
typedef short s16x4 __attribute__((ext_vector_type(4)));

typedef __attribute__((address_space(1))) const unsigned int g_u32;
typedef __attribute__((address_space(3))) unsigned int lds_u32;

__device__ __forceinline__ unsigned short bf16_rn(float f) {
    unsigned u = __float_as_uint(f);
    u += 0x7FFF + ((u >> 16) & 1);          // round-to-nearest-even
    return (unsigned short)(u >> 16);
}
__device__ __forceinline__ float bf16_to_f(unsigned short h) {
    return __uint_as_float(((unsigned)h) << 16);
}

// ---------------- K0: convert to hi/lo bf16 (fragment-swizzled) + row norms ----------------
// x: 256-row tiles [tile][kt(8)][quad(4)][row(256)][8]; e: 128-row tiles [tile][kt][quad][row(128)][8]
__global__ __launch_bounds__(256) void convert_kernel(const float* __restrict__ x,
                                                      const float* __restrict__ emb,
                                                      float* __restrict__ xx,
                                                      float* __restrict__ ee,
                                                      short* __restrict__ xhi, short* __restrict__ xlo,
                                                      short* __restrict__ ehi, short* __restrict__ elo) {
    int wid = threadIdx.x >> 6, ln = threadIdx.x & 63;
    int row = blockIdx.x * 4 + wid;             // 0 .. 21503
    const float* src; float* nrm; short *hiA, *loA; int rl, tb, rows;
    if (row < N_TOK) {
        src = x + (size_t)row * E_DIM; nrm = xx + row;
        tb = row >> 8; rl = row & 255; rows = 256; hiA = xhi; loA = xlo;
    } else {
        int r = row - N_TOK;
        src = emb + (size_t)r * E_DIM; nrm = ee + r;
        tb = r >> 7; rl = r & 127; rows = 128; hiA = ehi; loA = elo;
    }
    f32x4 v = ((const f32x4*)src)[ln];          // k = ln*4 .. ln*4+3
    float s = v[0]*v[0] + v[1]*v[1] + v[2]*v[2] + v[3]*v[3];
    s16x4 h, l;
#pragma unroll
    for (int c = 0; c < 4; ++c) {
        unsigned short hh = bf16_rn(v[c]);
        h[c] = (short)hh;
        l[c] = (short)bf16_rn(v[c] - bf16_to_f(hh));
    }
    int kt = ln >> 3, q = (ln >> 1) & 3, kl4 = (ln & 1) * 4;
    size_t di = ((((size_t)tb * NKT + kt) * 4 + q) * rows + rl) * 8 + kl4;
    *(s16x4*)&hiA[di] = h;
    *(s16x4*)&loA[di] = l;
#pragma unroll
    for (int sh = 32; sh; sh >>= 1) s += __shfl_xor(s, sh, 64);
    if (ln == 0) *nrm = s;
}

// ---------------- K1: distance GEMM (256x128: halves B re-staging = the HBM-read term) ----------------
// Round-7/8 theory: GEMM is HBM-traffic-bound (writes 469 MB NT + B-reads; A is L2-resident per
// XCD via swizzle). Doubling BM halves the number of B stagings: B traffic 402->201 MB.
// Retained (all verified): single-buffered __syncthreads staging, XCD swizzle, swapped-operand
// f32x4 epilogue, NT stores, hh->hl->lh term order (bit-identical outputs), 2 blocks/CU.
__global__ __launch_bounds__(256, 2) void gemm_kernel(const short* __restrict__ xhi,
                                                      const short* __restrict__ xlo,
                                                      const short* __restrict__ ehi,
                                                      const short* __restrict__ elo,
                                                      const int* __restrict__ split,
                                                      const float* __restrict__ xx,
                                                      const float* __restrict__ ee,
                                                      float* __restrict__ out,
                                                      float* __restrict__ pmin,
                                                      int*   __restrict__ pidx) {
    __shared__ short Ah[CHUNK_A], Al[CHUNK_A];      // 32 KB
    __shared__ short Bh[CHUNK_B], Bl[CHUNK_B];      // 16 KB
    __shared__ float xxs[BM];
    __shared__ float ees[BN];
    __shared__ float redv[2][BM];
    __shared__ int   redi[2][BM];

    // T1 XCD-aware swizzle (NBLK % 8 == 0 -> bijective): XCD k owns s in [k*320,(k+1)*320)
    // = 8 by-values x 40 bx -> per-XCD A footprint 8 x 262 KB = 2.1 MB (L2-resident).
    const int lin = blockIdx.y * NCB + blockIdx.x;
    const int s_  = (lin & 7) * (NBLK / 8) + (lin >> 3);
    const int bx = s_ % NCB;        // code block 0..39
    const int by = s_ / NCB;        // token block 0..63
    const int m0 = by * BM, n0 = bx * BN;
    const int t = threadIdx.x;

    const int s1 = split[1], s2v = split[2];
    const int tmFirst = (m0 >= s1) + (m0 >= s2v);     // 256-row blocks modality-uniform (5120%256==0)
    const int cmod = (n0 < N_SHARED) ? -1 : ((n0 - N_SHARED) >> 10);

    float* dOut = out + D_OFF;

    // fully-masked block: pure BIG fill (nt, lane-contiguous), no GEMM. 256x128 f32 = 8192 x4
    if (cmod >= 0 && cmod != tmFirst) {
        f32x4 big = {BIGF, BIGF, BIGF, BIGF};
#pragma unroll
        for (int u = 0; u < 32; ++u) {
            int idx = u * 256 + t;              // 0 .. 8191 f32x4 positions
            int row = idx >> 5, col4 = idx & 31;
            __builtin_nontemporal_store(big,
                (f32x4*)(dOut + (size_t)(m0 + row) * N_CODE + n0) + col4);
        }
        if (t < BM) {
            pmin[(size_t)(m0 + t) * NCB + bx] = BIGF;
            pidx[(size_t)(m0 + t) * NCB + bx] = n0;
        }
        return;
    }

    xxs[t] = xx[m0 + t];
    if (t < BN) ees[t] = ee[n0 + t];

    f32x4 acc[8][4] = {};

    const int wid = t >> 6, lane = t & 63;
    const int quad = lane >> 4, ln16 = lane & 15;
    const int wr = (wid >> 1) * 128, wc = (wid & 1) * 64;  // wave: 128 tokens x 64 codes

    const short* aHiG = xhi + (size_t)by * NKT * CHUNK_A;
    const short* aLoG = xlo + (size_t)by * NKT * CHUNK_A;
    const short* bHiG = ehi + (size_t)bx * NKT * CHUNK_B;
    const short* bLoG = elo + (size_t)bx * NKT * CHUNK_B;
    const int tOff = t * 8;                     // shorts (16 B per thread per round)

    for (int kt = 0; kt < NKT; ++kt) {
        __syncthreads();                        // previous iter's LDS reads done (also covers xxs/ees)
        const size_t coA = (size_t)kt * CHUNK_A;
        const size_t coB = (size_t)kt * CHUNK_B;
#pragma unroll
        for (int p = 0; p < 4; ++p) {           // A: 8192 shorts per stream = 4 rounds
            int o = p * 2048 + tOff;
            __builtin_amdgcn_global_load_lds((g_u32*)(aHiG + coA + o), (lds_u32*)&Ah[o], 16, 0, 0);
            __builtin_amdgcn_global_load_lds((g_u32*)(aLoG + coA + o), (lds_u32*)&Al[o], 16, 0, 0);
        }
#pragma unroll
        for (int p = 0; p < 2; ++p) {           // B: 4096 shorts per stream = 2 rounds
            int o = p * 2048 + tOff;
            __builtin_amdgcn_global_load_lds((g_u32*)(bHiG + coB + o), (lds_u32*)&Bh[o], 16, 0, 0);
            __builtin_amdgcn_global_load_lds((g_u32*)(bLoG + coB + o), (lds_u32*)&Bl[o], 16, 0, 0);
        }
        __syncthreads();                        // full drain: all staging loads landed

        // phase 1: hh
        bf16x8 ah[8], bh[4];
#pragma unroll
        for (int i = 0; i < 8; ++i)
            ah[i] = *(const bf16x8*)&Ah[(quad * BM + wr + i * 16 + ln16) * 8];
#pragma unroll
        for (int j = 0; j < 4; ++j)
            bh[j] = *(const bf16x8*)&Bh[(quad * BN + wc + j * 16 + ln16) * 8];
        __builtin_amdgcn_s_setprio(1);
#pragma unroll
        for (int i = 0; i < 8; ++i)
#pragma unroll
            for (int j = 0; j < 4; ++j)
                acc[i][j] = __builtin_amdgcn_mfma_f32_16x16x32_bf16(bh[j], ah[i], acc[i][j], 0, 0, 0);
        __builtin_amdgcn_s_setprio(0);

        // phase 2: hl (A_hi x B_lo) -- same accumulation order as previous rounds
        bf16x8 bl[4];
#pragma unroll
        for (int j = 0; j < 4; ++j)
            bl[j] = *(const bf16x8*)&Bl[(quad * BN + wc + j * 16 + ln16) * 8];
        __builtin_amdgcn_s_setprio(1);
#pragma unroll
        for (int i = 0; i < 8; ++i)
#pragma unroll
            for (int j = 0; j < 4; ++j)
                acc[i][j] = __builtin_amdgcn_mfma_f32_16x16x32_bf16(bl[j], ah[i], acc[i][j], 0, 0, 0);
        __builtin_amdgcn_s_setprio(0);

        // phase 3: lh (A_lo x B_hi)
        bf16x8 al[8];
#pragma unroll
        for (int i = 0; i < 8; ++i)
            al[i] = *(const bf16x8*)&Al[(quad * BM + wr + i * 16 + ln16) * 8];
        __builtin_amdgcn_s_setprio(1);
#pragma unroll
        for (int i = 0; i < 8; ++i)
#pragma unroll
            for (int j = 0; j < 4; ++j)
                acc[i][j] = __builtin_amdgcn_mfma_f32_16x16x32_bf16(bh[j], al[i], acc[i][j], 0, 0, 0);
        __builtin_amdgcn_s_setprio(0);
    }

    // epilogue: d = xx + ee - 2*dot, f32x4 nt-store along row, row-argmin over this block.
    // Swapped C/D layout: token = wr + i*16 + ln16, codes = wc + j*16 + quad*4 + r (r = reg).
#pragma unroll
    for (int i = 0; i < 8; ++i) {
        const int lt = wr + i * 16 + ln16;          // local token row
        const int gt = m0 + lt;
        const float xv = xxs[lt];
        float best = 3.4e38f;
        int bidx = n0;
#pragma unroll
        for (int j = 0; j < 4; ++j) {
            const int cb = wc + j * 16 + quad * 4;  // local code base (x4-aligned)
            f32x4 dv;
#pragma unroll
            for (int r = 0; r < 4; ++r) {
                float v = fmaf(-2.f, acc[i][j][r], xv + ees[cb + r]);
                dv[r] = v;
                if (v < best) { best = v; bidx = n0 + cb + r; }  // ascending code: ties keep lowest
            }
            __builtin_nontemporal_store(dv, (f32x4*)(dOut + (size_t)gt * N_CODE + n0 + cb));
        }
        // reduce across quads (lanes +-16, +-32 share the same token)
#pragma unroll
        for (int s = 16; s < 64; s <<= 1) {
            float ov = __shfl_xor(best, s, 64);
            int   oi = __shfl_xor(bidx, s, 64);
            if (ov < best || (ov == best && oi < bidx)) { best = ov; bidx = oi; }
        }
        if (quad == 0) { redv[wid & 1][lt] = best; redi[wid & 1][lt] = bidx; }
    }
    __syncthreads();
    if (t < BM) {
        float v0 = redv[0][t]; int i0 = redi[0][t];
        float v1 = redv[1][t]; int i1 = redi[1][t];
        if (v1 < v0 || (v1 == v0 && i1 < i0)) { v0 = v1; i0 = i1; }
        pmin[(size_t)(m0 + t) * NCB + bx] = v0;
        pidx[(size_t)(m0 + t) * NCB + bx] = i0;
    }
}

// ---------------- K2: per-token argmin over 40 partials + gather x_q, STE, loss partials ----------------
__global__ __launch_bounds__(256) void gather_kernel(const float* __restrict__ x,
                                                     const float* __restrict__ emb,
                                                     const int* __restrict__ split,
                                                     float* __restrict__ out,
                                                     const float* __restrict__ pmin,
                                                     const int* __restrict__ pidx,
                                                     float* __restrict__ wsLoss) {
    __shared__ float ls[3];
    int t = threadIdx.x, wid = t >> 6, ln = t & 63;
    if (t < 3) ls[t] = 0.f;
    __syncthreads();
    int tok = blockIdx.x * 4 + wid;

    // wave-wide argmin over this token's NCB partials (lanes >= NCB carry sentinels)
    float best = 3.4e38f;
    int bi = 0x7fffffff;
    if (ln < NCB) {
        best = pmin[(size_t)tok * NCB + ln];
        bi   = pidx[(size_t)tok * NCB + ln];
    }
#pragma unroll
    for (int sh = 32; sh; sh >>= 1) {
        float ov = __shfl_xor(best, sh, 64);
        int   oi = __shfl_xor(bi, sh, 64);
        if (ov < best || (ov == best && oi < bi)) { best = ov; bi = oi; }
    }
    if (ln == 0) out[IDX_OFF + tok] = (float)bi;
    int idx = bi;

    f32x4 e  = ((const f32x4*)(emb + (size_t)idx * E_DIM))[ln];
    f32x4 xv = ((const f32x4*)(x + (size_t)tok * E_DIM))[ln];
    f32x4 q;
    float s = 0.f;
#pragma unroll
    for (int c = 0; c < 4; ++c) {
        float d = e[c] - xv[c];
        q[c] = xv[c] + d;               // straight-through: x + (x_q - x)
        s = fmaf(d, d, s);
    }
    __builtin_nontemporal_store(q, (f32x4*)(out + (size_t)tok * E_DIM) + ln);
#pragma unroll
    for (int sh = 32; sh; sh >>= 1) s += __shfl_xor(s, sh, 64);
    if (ln == 0) {
        int mod = (tok >= split[1]) + (tok >= split[2]);
        atomicAdd(&ls[mod], s);
    }
    __syncthreads();
    if (t < 3) wsLoss[blockIdx.x * 3 + t] = ls[t];
}

// ---------------- K3: final loss reduction ----------------
__global__ __launch_bounds__(256) void loss_kernel(const float* __restrict__ wsLoss,
                                                   const int* __restrict__ split,
                                                   float* __restrict__ out, int nblk) {
    __shared__ float red[256];
    float s[3] = {0.f, 0.f, 0.f};
    for (int b = threadIdx.x; b < nblk; b += 256) {
        s[0] += wsLoss[b * 3 + 0];
        s[1] += wsLoss[b * 3 + 1];
        s[2] += wsLoss[b * 3 + 2];
    }
    for (int m = 0; m < 3; ++m) {
        red[threadIdx.x] = s[m];
        __syncthreads();
        for (int st = 128; st; st >>= 1) {
            if (threadIdx.x < st) red[threadIdx.x] += red[threadIdx.x + st];
            __syncthreads();
        }
        if (threadIdx.x == 0) {
            float cnt = (float)(split[m + 1] - split[m]) * (float)E_DIM;
            float a = red[0] / cnt;
            out[QL_OFF + m] = a + 0.25f * a;   // code + beta*commit (numerically equal)
        }
        __syncthreads();
    }
}

extern "C" void kernel_launch(void* const* d_in, const int* in_sizes, int n_in,
                              void* d_out, int out_size, void* d_ws, size_t ws_size,
                              hipStream_t stream) {
    const float* x   = (const float*)d_in[0];
    const float* emb = (const float*)d_in[1];
    const int* split = (const int*)d_in[2];
    float* out = (float*)d_out;

    float* xx     = (float*)d_ws;                          // 16384 f32
    float* ee     = xx + N_TOK;                            // 5120 f32
    float* wsLoss = ee + N_CODE;                           // 4096*3 f32
    float* pmin   = wsLoss + 4096 * 3;                     // 16384*40 f32
    int*   pidx   = (int*)(pmin + (size_t)N_TOK * NCB);    // 16384*40 i32
    short* xhi    = (short*)(pidx + (size_t)N_TOK * NCB);
    short* xlo    = xhi + (size_t)N_TOK * E_DIM;
    short* ehi    = xlo + (size_t)N_TOK * E_DIM;
    short* elo    = ehi + (size_t)N_CODE * E_DIM;
    int nblkGather = N_TOK / 4;            // 4096

    convert_kernel<<<dim3((N_TOK + N_CODE) / 4), dim3(256), 0, stream>>>(x, emb, xx, ee, xhi, xlo, ehi, elo);
    gemm_kernel<<<dim3(NCB, N_TOK / BM), dim3(256), 0, stream>>>(xhi, xlo, ehi, elo, split, xx, ee, out, pmin, pidx);
    gather_kernel<<<dim3(nblkGather), dim3(256), 0, stream>>>(x, emb, split, out, pmin, pidx, wsLoss);
    loss_kernel<<<dim3(1), dim3(256), 0, stream>>>(wsLoss, split, out, nblkGather);
}